// Round 7
// baseline (197.972 us; speedup 1.0000x reference)
//
#include <hip/hip_runtime.h>
#include <hip/hip_bf16.h>
#include <math.h>

#define EMB 128
#define HID 128
#define NCOL 256   // src-proj(128, b1 folded) ++ dst-proj(128)

typedef __attribute__((ext_vector_type(8))) short short8v;   // 8 bf16 = 4 VGPR
typedef __attribute__((ext_vector_type(4))) float f32x4;     // MFMA acc

__device__ __forceinline__ unsigned short f2bf(float f) {
    union { float f; unsigned int u; } v; v.f = f;
    unsigned int r = (v.u + 0x7FFFu + ((v.u >> 16) & 1u)) >> 16;
    return (unsigned short)r;
}
__device__ __forceinline__ float bf2f(unsigned int u16) {
    return __uint_as_float(u16 << 16);
}

// 16-lane sum via DPP (pure VALU, no DS). Patterns stay within the 16-lane
// row, so inactive sibling slots in the wave can't leak in.
template<int CTRL>
__device__ __forceinline__ float dpp_add(float x) {
    int y = __builtin_amdgcn_update_dpp(0, __float_as_int(x), CTRL, 0xf, 0xf, true);
    return x + __int_as_float(y);
}
__device__ __forceinline__ float red16(float x) {
    x = dpp_add<0xB1>(x);    // quad_perm [1,0,3,2]  (xor 1)
    x = dpp_add<0x4E>(x);    // quad_perm [2,3,0,1]  (xor 2)
    x = dpp_add<0x141>(x);   // row_half_mirror      (xor-ish 4..7)
    x = dpp_add<0x140>(x);   // row_mirror           (combine halves of 16)
    return x;
}

// ---------------------------------------------------------------------------
// Kernel 0: Wt[c][k] (bf16) = combined-W1 transposed:
//   c<128 : W1[k][c] ; c>=128: W1[128+k][c-128]
// ---------------------------------------------------------------------------
__global__ __launch_bounds__(256) void w_prep(
    const float* __restrict__ W1, unsigned short* __restrict__ Wt)
{
    int idx = blockIdx.x * 256 + threadIdx.x;      // 0..32767
    int c = idx >> 7;          // 0..255
    int k = idx & 127;         // 0..127
    float v = W1[(size_t)(k + ((c >> 7) << 7)) * HID + (c & 127)];
    Wt[idx] = f2bf(v);
}

// ---------------------------------------------------------------------------
// Kernel 1: P[n][c] (bf16) via MFMA 16x16x32, W as A-operand, nodes as B.
// 2-deep software pipeline: tile t+1's node floats prefetched into registers
// while tile t computes, so HBM latency hides under compute.
// b1 folded into channels 0..127 before bf16 rounding.
// ---------------------------------------------------------------------------
__global__ __launch_bounds__(256) void proj_mfma(
    const float* __restrict__ A,          // [N][128] f32
    const unsigned short* __restrict__ Wt,// [256][128] bf16
    const float* __restrict__ b1,         // [128]
    unsigned short* __restrict__ P,       // [N][256] bf16
    int N, int nTiles)
{
    const int w    = threadIdx.x >> 6;    // wave 0..3
    const int lane = threadIdx.x & 63;
    const int l16  = lane & 15;
    const int lk   = lane >> 4;           // 0..3

    // W fragments: afrag[cf][ks]; channel c = 64w+16cf+l16, k = 32ks+8lk+i
    short8v afrag[4][4];
#pragma unroll
    for (int cf = 0; cf < 4; ++cf)
#pragma unroll
        for (int ks = 0; ks < 4; ++ks) {
            int c = 64 * w + 16 * cf + l16;
            afrag[cf][ks] = *(const short8v*)(Wt + (size_t)c * EMB + 32 * ks + 8 * lk);
        }

    // b1 fold: this lane's 4 channels per cf start at 64w+16cf+4lk
    float4 b1v[4];
#pragma unroll
    for (int cf = 0; cf < 4; ++cf) {
        if (w < 2) b1v[cf] = *(const float4*)(b1 + 64 * w + 16 * cf + 4 * lk);
        else       b1v[cf] = make_float4(0.f, 0.f, 0.f, 0.f);
    }

    int t = blockIdx.x;
    if (t >= nTiles) return;

    // prologue: prefetch tile t
    float4 fbuf[8];
    {
        int node = t * 16 + l16;
        int nc   = node < N ? node : N - 1;
        const float* ap = A + (size_t)nc * EMB + 8 * lk;
#pragma unroll
        for (int ks = 0; ks < 4; ++ks) {
            fbuf[2 * ks]     = *(const float4*)(ap + 32 * ks);
            fbuf[2 * ks + 1] = *(const float4*)(ap + 32 * ks + 4);
        }
    }

    for (; t < nTiles; t += gridDim.x) {
        // convert current tile's floats to bf16 fragments (consumes fbuf)
        short8v bf[4];
#pragma unroll
        for (int ks = 0; ks < 4; ++ks) {
            float4 a0 = fbuf[2 * ks], a1 = fbuf[2 * ks + 1];
            short8v f = { (short)f2bf(a0.x), (short)f2bf(a0.y), (short)f2bf(a0.z), (short)f2bf(a0.w),
                          (short)f2bf(a1.x), (short)f2bf(a1.y), (short)f2bf(a1.z), (short)f2bf(a1.w) };
            bf[ks] = f;
        }

        // prefetch NEXT tile into fbuf (overlaps with MFMA + epilogue below)
        int tn = t + gridDim.x;
        if (tn < nTiles) {
            int node = tn * 16 + l16;
            int nc   = node < N ? node : N - 1;
            const float* ap = A + (size_t)nc * EMB + 8 * lk;
#pragma unroll
            for (int ks = 0; ks < 4; ++ks) {
                fbuf[2 * ks]     = *(const float4*)(ap + 32 * ks);
                fbuf[2 * ks + 1] = *(const float4*)(ap + 32 * ks + 4);
            }
        }

        f32x4 acc[4];
#pragma unroll
        for (int cf = 0; cf < 4; ++cf) acc[cf] = (f32x4)0.0f;

#pragma unroll
        for (int ks = 0; ks < 4; ++ks)
#pragma unroll
            for (int cf = 0; cf < 4; ++cf)
                acc[cf] = __builtin_amdgcn_mfma_f32_16x16x32_bf16(
                    afrag[cf][ks], bf[ks], acc[cf], 0, 0, 0);

        // epilogue: node = t*16+l16 (col), channels 64w+16cf+4lk+r (row)
        int node = t * 16 + l16;
        if (node < N) {
            unsigned short* prow = P + (size_t)node * NCOL;
#pragma unroll
            for (int cf = 0; cf < 4; ++cf) {
                float v0 = acc[cf][0] + b1v[cf].x;
                float v1 = acc[cf][1] + b1v[cf].y;
                float v2 = acc[cf][2] + b1v[cf].z;
                float v3 = acc[cf][3] + b1v[cf].w;
                unsigned int u0 = (unsigned int)f2bf(v0) | ((unsigned int)f2bf(v1) << 16);
                unsigned int u1 = (unsigned int)f2bf(v2) | ((unsigned int)f2bf(v3) << 16);
                *(uint2*)(prow + 64 * w + 16 * cf + 4 * lk) = make_uint2(u0, u1);
            }
        }
    }
}

// ---------------------------------------------------------------------------
// Kernel 2: per-edge epilogue on bf16 P (b1 pre-folded). 16 lanes/edge,
// uint4 gathers, DPP reductions (no DS ops).
// ---------------------------------------------------------------------------
__global__ __launch_bounds__(256) void edge_kernel(
    const unsigned short* __restrict__ P,
    const int* __restrict__ ei,     // [2][E] int32
    const float* __restrict__ lng,
    const float* __restrict__ lnb,
    const float* __restrict__ W2,
    const float* __restrict__ b2,
    float* __restrict__ out, int E)
{
    const int l16 = threadIdx.x & 15;
    const int c0  = l16 * 8;

    float vg[8], vbt[8], vw2[8];
#pragma unroll
    for (int i = 0; i < 8; i += 4) {
        *(float4*)&vg[i]  = *(const float4*)(lng + c0 + i);
        *(float4*)&vbt[i] = *(const float4*)(lnb + c0 + i);
        *(float4*)&vw2[i] = *(const float4*)(W2  + c0 + i);
    }
    const float bias2 = b2[0];

    int slot   = blockIdx.x * (blockDim.x >> 4) + (threadIdx.x >> 4);
    int nslots = gridDim.x * (blockDim.x >> 4);

    for (int e = slot; e < E; e += nslots) {
        int src = ei[e];
        int dst = ei[E + e];
        uint4 us = *(const uint4*)(P + (size_t)src * NCOL + c0);
        uint4 ud = *(const uint4*)(P + (size_t)dst * NCOL + HID + c0);

        float h[8];
        {
            unsigned int uu[4] = {us.x, us.y, us.z, us.w};
            unsigned int dd[4] = {ud.x, ud.y, ud.z, ud.w};
#pragma unroll
            for (int j = 0; j < 4; ++j) {
                h[2 * j]     = bf2f(uu[j] & 0xFFFFu) + bf2f(dd[j] & 0xFFFFu);
                h[2 * j + 1] = __uint_as_float(uu[j] & 0xFFFF0000u) +
                               __uint_as_float(dd[j] & 0xFFFF0000u);
            }
        }
        float s = 0.0f, sq = 0.0f;
#pragma unroll
        for (int i = 0; i < 8; ++i) {
            s += h[i];
            sq = fmaf(h[i], h[i], sq);
        }
        s  = red16(s);
        sq = red16(sq);

        float mu  = s * (1.0f / HID);
        float var = sq * (1.0f / HID) - mu * mu;
        float r   = rsqrtf(var + 1e-5f);
        float nmr = -mu * r;

        float z = 0.0f;
#pragma unroll
        for (int i = 0; i < 8; ++i) {
            float t = fmaf(h[i], r, nmr);
            float y = fmaf(t, vg[i], vbt[i]);
            y = fmaxf(y, 0.0f);
            z = fmaf(y, vw2[i], z);
        }
        z = red16(z);

        if (l16 == 0) {
            float zz = z + bias2;
            float wv = 1.0f / (1.0f + expf(-zz));
            if (wv != wv) wv = 0.5f;   // nan_to_num(nan=0.5)
            out[e] = wv;
        }
    }
}

// ---------------------------------------------------------------------------
// Fallback (ws too small): fused per-edge matmul, slow but correct.
// ---------------------------------------------------------------------------
__global__ __launch_bounds__(256) void fused_kernel(
    const float* __restrict__ X,
    const int* __restrict__ ei,
    const float* __restrict__ W1,
    const float* __restrict__ b1,
    const float* __restrict__ lng,
    const float* __restrict__ lnb,
    const float* __restrict__ W2,
    const float* __restrict__ b2,
    float* __restrict__ out, int E)
{
    const int lane = threadIdx.x & 31;
    const int c0   = lane * 4;
    const float4 vb1 = *(const float4*)(b1  + c0);
    const float4 vg  = *(const float4*)(lng + c0);
    const float4 vbt = *(const float4*)(lnb + c0);
    const float4 vw2 = *(const float4*)(W2  + c0);
    const float bias2 = b2[0];

    int slot   = blockIdx.x * (blockDim.x >> 5) + (threadIdx.x >> 5);
    int nslots = gridDim.x * (blockDim.x >> 5);

    for (int e = slot; e < E; e += nslots) {
        int src = ei[e];
        int dst = ei[E + e];
        const float* xs = X + (size_t)src * EMB;
        const float* xd = X + (size_t)dst * EMB;
        float h0 = vb1.x, h1 = vb1.y, h2 = vb1.z, h3 = vb1.w;
        for (int k = 0; k < EMB; ++k) {
            float a  = xs[k];
            float4 w = *(const float4*)(W1 + (size_t)k * HID + c0);
            h0 = fmaf(a, w.x, h0); h1 = fmaf(a, w.y, h1);
            h2 = fmaf(a, w.z, h2); h3 = fmaf(a, w.w, h3);
        }
        for (int k = 0; k < EMB; ++k) {
            float a  = xd[k];
            float4 w = *(const float4*)(W1 + (size_t)(EMB + k) * HID + c0);
            h0 = fmaf(a, w.x, h0); h1 = fmaf(a, w.y, h1);
            h2 = fmaf(a, w.z, h2); h3 = fmaf(a, w.w, h3);
        }
        float s  = h0 + h1 + h2 + h3;
        float sq = h0 * h0 + h1 * h1 + h2 * h2 + h3 * h3;
#pragma unroll
        for (int m = 16; m >= 1; m >>= 1) {
            s  += __shfl_xor(s,  m, 32);
            sq += __shfl_xor(sq, m, 32);
        }
        float mu  = s * (1.0f / HID);
        float var = sq * (1.0f / HID) - mu * mu;
        float r   = rsqrtf(var + 1e-5f);
        float y0 = fmaxf(fmaf((h0 - mu) * r, vg.x, vbt.x), 0.0f);
        float y1 = fmaxf(fmaf((h1 - mu) * r, vg.y, vbt.y), 0.0f);
        float y2 = fmaxf(fmaf((h2 - mu) * r, vg.z, vbt.z), 0.0f);
        float y3 = fmaxf(fmaf((h3 - mu) * r, vg.w, vbt.w), 0.0f);
        float z = y0 * vw2.x + y1 * vw2.y + y2 * vw2.z + y3 * vw2.w;
#pragma unroll
        for (int m = 16; m >= 1; m >>= 1) z += __shfl_xor(z, m, 32);
        if (lane == 0) {
            float zz = z + bias2;
            float wv = 1.0f / (1.0f + expf(-zz));
            if (wv != wv) wv = 0.5f;
            out[e] = wv;
        }
    }
}

extern "C" void kernel_launch(void* const* d_in, const int* in_sizes, int n_in,
                              void* d_out, int out_size, void* d_ws, size_t ws_size,
                              hipStream_t stream) {
    const float* node_emb = (const float*)d_in[0];
    const int*   ei       = (const int*)d_in[1];
    const float* W1       = (const float*)d_in[2];
    const float* b1       = (const float*)d_in[3];
    const float* lng      = (const float*)d_in[4];
    const float* lnb      = (const float*)d_in[5];
    const float* W2       = (const float*)d_in[6];
    const float* b2       = (const float*)d_in[7];
    float* out = (float*)d_out;

    const int N = in_sizes[0] / EMB;   // 100000
    const int E = in_sizes[1] / 2;     // 800000

    const size_t pBytes = (size_t)N * NCOL * sizeof(unsigned short); // 51.2 MB
    const size_t need   = pBytes + (size_t)NCOL * EMB * sizeof(unsigned short);

    if (ws_size >= need) {
        unsigned short* P  = (unsigned short*)d_ws;
        unsigned short* Wt = (unsigned short*)((char*)d_ws + pBytes);

        w_prep<<<(NCOL * EMB) / 256, 256, 0, stream>>>(W1, Wt);

        int nTiles = (N + 15) / 16;                 // 6250
        int gridP  = nTiles < 2048 ? nTiles : 2048;
        proj_mfma<<<gridP, 256, 0, stream>>>(node_emb, Wt, b1, P, N, nTiles);

        edge_kernel<<<4096, 256, 0, stream>>>(P, ei, lng, lnb, W2, b2, out, E);
    } else {
        fused_kernel<<<2048, 256, 0, stream>>>(node_emb, ei, W1, b1, lng, lnb,
                                               W2, b2, out, E);
    }
}

// Round 11
// 182.961 us; speedup vs baseline: 1.0820x; 1.0820x over previous
//
#include <hip/hip_runtime.h>
#include <hip/hip_bf16.h>
#include <math.h>

#define EMB 128
#define HID 128
#define NCOL 256   // src-proj(128, b1 folded) ++ dst-proj(128)

typedef __attribute__((ext_vector_type(8))) short short8v;   // 8 bf16 = 4 VGPR
typedef __attribute__((ext_vector_type(4))) float f32x4;     // MFMA acc

__device__ __forceinline__ unsigned short f2bf(float f) {
    union { float f; unsigned int u; } v; v.f = f;
    unsigned int r = (v.u + 0x7FFFu + ((v.u >> 16) & 1u)) >> 16;
    return (unsigned short)r;
}
__device__ __forceinline__ float bf2f(unsigned int u16) {
    return __uint_as_float(u16 << 16);
}

// 16-lane sum via DPP (pure VALU, no DS). Patterns stay within the 16-lane
// row, so inactive sibling slots in the wave can't leak in.
template<int CTRL>
__device__ __forceinline__ float dpp_add(float x) {
    int y = __builtin_amdgcn_update_dpp(0, __float_as_int(x), CTRL, 0xf, 0xf, true);
    return x + __int_as_float(y);
}
__device__ __forceinline__ float red16(float x) {
    x = dpp_add<0xB1>(x);    // quad_perm [1,0,3,2]  (xor 1)
    x = dpp_add<0x4E>(x);    // quad_perm [2,3,0,1]  (xor 2)
    x = dpp_add<0x141>(x);   // row_half_mirror
    x = dpp_add<0x140>(x);   // row_mirror (combine halves of 16)
    return x;
}

// ---------------------------------------------------------------------------
// Kernel 0: Wt[c][k] (bf16) = combined-W1 transposed:
//   c<128 : W1[k][c] ; c>=128: W1[128+k][c-128]
// ---------------------------------------------------------------------------
__global__ __launch_bounds__(256) void w_prep(
    const float* __restrict__ W1, unsigned short* __restrict__ Wt)
{
    int idx = blockIdx.x * 256 + threadIdx.x;      // 0..32767
    int c = idx >> 7;          // 0..255
    int k = idx & 127;         // 0..127
    float v = W1[(size_t)(k + ((c >> 7) << 7)) * HID + (c & 127)];
    Wt[idx] = f2bf(v);
}

// ---------------------------------------------------------------------------
// Kernel 1 (v3): P[n][c] bf16 via MFMA 16x16x32, LDS-staged node tiles.
// Block = 4 waves, one 64-node tile. Stage tile to LDS ONCE (coalesced,
// bf16, XOR-swizzled rows: byte ^= (row&7)<<4 -> ds_read_b128 B-frags are
// 2-way-conflict-free). Wave w computes channels 64w..64w+63 for all 64
// nodes (4 node-groups x 16 MFMA), storing each group's acc immediately.
// A-traffic: 51.2 MB total (was 205 MB with per-wave redundant loads).
// ---------------------------------------------------------------------------
__global__ __launch_bounds__(256) void proj_mfma(
    const float* __restrict__ A,          // [N][128] f32
    const unsigned short* __restrict__ Wt,// [256][128] bf16
    const float* __restrict__ b1,         // [128]
    unsigned short* __restrict__ P,       // [N][256] bf16
    int N, int nTiles)
{
    __shared__ unsigned short lds_bf[64 * 128];   // 16 KB, swizzled
    char* ldsb = (char*)lds_bf;

    const int tid  = threadIdx.x;
    const int w    = tid >> 6;            // wave 0..3
    const int lane = tid & 63;
    const int l16  = lane & 15;
    const int lk   = lane >> 4;           // 0..3

    const int t = blockIdx.x;
    if (t >= nTiles) return;
    const int n0 = t * 64;

    // ---- W fragments: afrag[cf][ks]; channel c = 64w+16cf+l16 ----
    short8v afrag[4][4];
#pragma unroll
    for (int cf = 0; cf < 4; ++cf)
#pragma unroll
        for (int ks = 0; ks < 4; ++ks) {
            int c = 64 * w + 16 * cf + l16;
            afrag[cf][ks] = *(const short8v*)(Wt + (size_t)c * EMB + 32 * ks + 8 * lk);
        }

    // ---- b1 fold (channels < 128 only, i.e. waves 0,1) ----
    float4 b1v[4];
#pragma unroll
    for (int cf = 0; cf < 4; ++cf) {
        if (w < 2) b1v[cf] = *(const float4*)(b1 + 64 * w + 16 * cf + 4 * lk);
        else       b1v[cf] = make_float4(0.f, 0.f, 0.f, 0.f);
    }

    // ---- stage: 2048 float4s (64 rows x 32 f4/row), 8 per thread ----
#pragma unroll
    for (int i = 0; i < 8; ++i) {
        int g   = tid + 256 * i;          // float4 id
        int row = g >> 5;                 // 0..63
        int c4  = g & 31;                 // float4 within row
        int nc  = n0 + row; nc = nc < N ? nc : N - 1;
        float4 v = *(const float4*)(A + (size_t)nc * EMB + c4 * 4);
        unsigned int u0 = (unsigned int)f2bf(v.x) | ((unsigned int)f2bf(v.y) << 16);
        unsigned int u1 = (unsigned int)f2bf(v.z) | ((unsigned int)f2bf(v.w) << 16);
        int byte = (row << 8) + (c4 << 3);
        byte ^= (row & 7) << 4;           // swizzle
        *(uint2*)(ldsb + byte) = make_uint2(u0, u1);
    }
    __syncthreads();

    // ---- compute: 4 node-groups, store each immediately ----
#pragma unroll
    for (int ng = 0; ng < 4; ++ng) {
        int node_l = 16 * ng + l16;       // local node this lane owns (B col)
        short8v bfr[4];
#pragma unroll
        for (int ks = 0; ks < 4; ++ks) {
            int byte = (node_l << 8) + ((32 * ks + 8 * lk) << 1);
            byte ^= (node_l & 7) << 4;
            bfr[ks] = *(const short8v*)(ldsb + byte);   // ds_read_b128
        }
        f32x4 acc[4];
#pragma unroll
        for (int cf = 0; cf < 4; ++cf) acc[cf] = (f32x4)0.0f;
#pragma unroll
        for (int ks = 0; ks < 4; ++ks)
#pragma unroll
            for (int cf = 0; cf < 4; ++cf)
                acc[cf] = __builtin_amdgcn_mfma_f32_16x16x32_bf16(
                    afrag[cf][ks], bfr[ks], acc[cf], 0, 0, 0);

        int node = n0 + node_l;
        if (node < N) {
            unsigned short* prow = P + (size_t)node * NCOL;
#pragma unroll
            for (int cf = 0; cf < 4; ++cf) {
                float v0 = acc[cf][0] + b1v[cf].x;
                float v1 = acc[cf][1] + b1v[cf].y;
                float v2 = acc[cf][2] + b1v[cf].z;
                float v3 = acc[cf][3] + b1v[cf].w;
                unsigned int u0 = (unsigned int)f2bf(v0) | ((unsigned int)f2bf(v1) << 16);
                unsigned int u1 = (unsigned int)f2bf(v2) | ((unsigned int)f2bf(v3) << 16);
                *(uint2*)(prow + 64 * w + 16 * cf + 4 * lk) = make_uint2(u0, u1);
            }
        }
    }
}

// ---------------------------------------------------------------------------
// Kernel 2: per-edge epilogue on bf16 P (b1 pre-folded). 16 lanes/edge,
// uint4 gathers, DPP reductions (no DS ops). UNCHANGED from R7.
// ---------------------------------------------------------------------------
__global__ __launch_bounds__(256) void edge_kernel(
    const unsigned short* __restrict__ P,
    const int* __restrict__ ei,     // [2][E] int32
    const float* __restrict__ lng,
    const float* __restrict__ lnb,
    const float* __restrict__ W2,
    const float* __restrict__ b2,
    float* __restrict__ out, int E)
{
    const int l16 = threadIdx.x & 15;
    const int c0  = l16 * 8;

    float vg[8], vbt[8], vw2[8];
#pragma unroll
    for (int i = 0; i < 8; i += 4) {
        *(float4*)&vg[i]  = *(const float4*)(lng + c0 + i);
        *(float4*)&vbt[i] = *(const float4*)(lnb + c0 + i);
        *(float4*)&vw2[i] = *(const float4*)(W2  + c0 + i);
    }
    const float bias2 = b2[0];

    int slot   = blockIdx.x * (blockDim.x >> 4) + (threadIdx.x >> 4);
    int nslots = gridDim.x * (blockDim.x >> 4);

    for (int e = slot; e < E; e += nslots) {
        int src = ei[e];
        int dst = ei[E + e];
        uint4 us = *(const uint4*)(P + (size_t)src * NCOL + c0);
        uint4 ud = *(const uint4*)(P + (size_t)dst * NCOL + HID + c0);

        float h[8];
        {
            unsigned int uu[4] = {us.x, us.y, us.z, us.w};
            unsigned int dd[4] = {ud.x, ud.y, ud.z, ud.w};
#pragma unroll
            for (int j = 0; j < 4; ++j) {
                h[2 * j]     = bf2f(uu[j] & 0xFFFFu) + bf2f(dd[j] & 0xFFFFu);
                h[2 * j + 1] = __uint_as_float(uu[j] & 0xFFFF0000u) +
                               __uint_as_float(dd[j] & 0xFFFF0000u);
            }
        }
        float s = 0.0f, sq = 0.0f;
#pragma unroll
        for (int i = 0; i < 8; ++i) {
            s += h[i];
            sq = fmaf(h[i], h[i], sq);
        }
        s  = red16(s);
        sq = red16(sq);

        float mu  = s * (1.0f / HID);
        float var = sq * (1.0f / HID) - mu * mu;
        float r   = rsqrtf(var + 1e-5f);
        float nmr = -mu * r;

        float z = 0.0f;
#pragma unroll
        for (int i = 0; i < 8; ++i) {
            float t = fmaf(h[i], r, nmr);
            float y = fmaf(t, vg[i], vbt[i]);
            y = fmaxf(y, 0.0f);
            z = fmaf(y, vw2[i], z);
        }
        z = red16(z);

        if (l16 == 0) {
            float zz = z + bias2;
            float wv = 1.0f / (1.0f + expf(-zz));
            if (wv != wv) wv = 0.5f;   // nan_to_num(nan=0.5)
            out[e] = wv;
        }
    }
}

// ---------------------------------------------------------------------------
// Fallback (ws too small): fused per-edge matmul, slow but correct.
// ---------------------------------------------------------------------------
__global__ __launch_bounds__(256) void fused_kernel(
    const float* __restrict__ X,
    const int* __restrict__ ei,
    const float* __restrict__ W1,
    const float* __restrict__ b1,
    const float* __restrict__ lng,
    const float* __restrict__ lnb,
    const float* __restrict__ W2,
    const float* __restrict__ b2,
    float* __restrict__ out, int E)
{
    const int lane = threadIdx.x & 31;
    const int c0   = lane * 4;
    const float4 vb1 = *(const float4*)(b1  + c0);
    const float4 vg  = *(const float4*)(lng + c0);
    const float4 vbt = *(const float4*)(lnb + c0);
    const float4 vw2 = *(const float4*)(W2  + c0);
    const float bias2 = b2[0];

    int slot   = blockIdx.x * (blockDim.x >> 5) + (threadIdx.x >> 5);
    int nslots = gridDim.x * (blockDim.x >> 5);

    for (int e = slot; e < E; e += nslots) {
        int src = ei[e];
        int dst = ei[E + e];
        const float* xs = X + (size_t)src * EMB;
        const float* xd = X + (size_t)dst * EMB;
        float h0 = vb1.x, h1 = vb1.y, h2 = vb1.z, h3 = vb1.w;
        for (int k = 0; k < EMB; ++k) {
            float a  = xs[k];
            float4 w = *(const float4*)(W1 + (size_t)k * HID + c0);
            h0 = fmaf(a, w.x, h0); h1 = fmaf(a, w.y, h1);
            h2 = fmaf(a, w.z, h2); h3 = fmaf(a, w.w, h3);
        }
        for (int k = 0; k < EMB; ++k) {
            float a  = xd[k];
            float4 w = *(const float4*)(W1 + (size_t)(EMB + k) * HID + c0);
            h0 = fmaf(a, w.x, h0); h1 = fmaf(a, w.y, h1);
            h2 = fmaf(a, w.z, h2); h3 = fmaf(a, w.w, h3);
        }
        float s  = h0 + h1 + h2 + h3;
        float sq = h0 * h0 + h1 * h1 + h2 * h2 + h3 * h3;
#pragma unroll
        for (int m = 16; m >= 1; m >>= 1) {
            s  += __shfl_xor(s,  m, 32);
            sq += __shfl_xor(sq, m, 32);
        }
        float mu  = s * (1.0f / HID);
        float var = sq * (1.0f / HID) - mu * mu;
        float r   = rsqrtf(var + 1e-5f);
        float y0 = fmaxf(fmaf((h0 - mu) * r, vg.x, vbt.x), 0.0f);
        float y1 = fmaxf(fmaf((h1 - mu) * r, vg.y, vbt.y), 0.0f);
        float y2 = fmaxf(fmaf((h2 - mu) * r, vg.z, vbt.z), 0.0f);
        float y3 = fmaxf(fmaf((h3 - mu) * r, vg.w, vbt.w), 0.0f);
        float z = y0 * vw2.x + y1 * vw2.y + y2 * vw2.z + y3 * vw2.w;
#pragma unroll
        for (int m = 16; m >= 1; m >>= 1) z += __shfl_xor(z, m, 32);
        if (lane == 0) {
            float zz = z + bias2;
            float wv = 1.0f / (1.0f + expf(-zz));
            if (wv != wv) wv = 0.5f;
            out[e] = wv;
        }
    }
}

extern "C" void kernel_launch(void* const* d_in, const int* in_sizes, int n_in,
                              void* d_out, int out_size, void* d_ws, size_t ws_size,
                              hipStream_t stream) {
    const float* node_emb = (const float*)d_in[0];
    const int*   ei       = (const int*)d_in[1];
    const float* W1       = (const float*)d_in[2];
    const float* b1       = (const float*)d_in[3];
    const float* lng      = (const float*)d_in[4];
    const float* lnb      = (const float*)d_in[5];
    const float* W2       = (const float*)d_in[6];
    const float* b2       = (const float*)d_in[7];
    float* out = (float*)d_out;

    const int N = in_sizes[0] / EMB;   // 100000
    const int E = in_sizes[1] / 2;     // 800000

    const size_t pBytes = (size_t)N * NCOL * sizeof(unsigned short); // 51.2 MB
    const size_t need   = pBytes + (size_t)NCOL * EMB * sizeof(unsigned short);

    if (ws_size >= need) {
        unsigned short* P  = (unsigned short*)d_ws;
        unsigned short* Wt = (unsigned short*)((char*)d_ws + pBytes);

        w_prep<<<(NCOL * EMB) / 256, 256, 0, stream>>>(W1, Wt);

        int nTiles = (N + 63) / 64;                 // 1563
        proj_mfma<<<nTiles, 256, 0, stream>>>(node_emb, Wt, b1, P, N, nTiles);

        edge_kernel<<<4096, 256, 0, stream>>>(P, ei, lng, lnb, W2, b2, out, E);
    } else {
        fused_kernel<<<2048, 256, 0, stream>>>(node_emb, ei, W1, b1, lng, lnb,
                                               W2, b2, out, E);
    }
}